// Round 4
// baseline (186.636 us; speedup 1.0000x reference)
//
#include <hip/hip_runtime.h>

typedef unsigned long long u64;

#define NIMG 4
#define H 256
#define W 256
#define NPIX (H*W)           // 65536 per image
#define NTOT (NIMG*NPIX)     // 262144
#define WPR 4                // u64 words per row (256 bits)
#define WPI (H*WPR)          // 1024 words per image
#define WPB (NIMG*WPI)       // 4096 words per branch

// ---------------------------------------------------------------------------
// K1: pp = sigmoid(2*sigmoid(y_pred)-1); pack yt and (pp>0.5) bitmasks.
// One wave (64 lanes) covers 64 consecutive pixels -> __ballot packs a word.
// Block 0 also initializes rmm (atomic identities), sums, and block counter.
// ---------------------------------------------------------------------------
__global__ void prep_kernel(const float* __restrict__ y_pred,
                            const int* __restrict__ y_true,
                            float* __restrict__ pp,
                            u64* __restrict__ mask_bits,
                            unsigned* __restrict__ rmm_u,
                            double* __restrict__ sums,
                            unsigned* __restrict__ count) {
  if (blockIdx.x == 0) {
    if (threadIdx.x < 16) rmm_u[threadIdx.x] = (threadIdx.x & 1) ? 0x7F800000u : 0u; // min:+inf, max:0
    else if (threadIdx.x < 20) sums[threadIdx.x - 16] = 0.0;
    else if (threadIdx.x == 20) *count = 0u;
  }
  int i = blockIdx.x * 256 + threadIdx.x;
  float x = y_pred[i];
  float p = 1.0f / (1.0f + expf(-x));
  float q = 1.0f / (1.0f + expf(-(2.0f * p - 1.0f)));
  pp[i] = q;
  u64 bt = __ballot(y_true[i] > 0);
  u64 bp = __ballot(q > 0.5f);
  if ((threadIdx.x & 63) == 0) {
    mask_bits[i >> 6] = bt;          // branch 0: true mask
    mask_bits[WPB + (i >> 6)] = bp;  // branch 1: pred hard mask
  }
}

// ---------------------------------------------------------------------------
// Bit-parallel morphology helpers. Bit b of word k = pixel x = 64k+b.
// Erode = AND over cross {c, up, down, left, right}, OOB treated as 1.
// Dilate = OR over 3x3 box, OOB treated as 0.
// ---------------------------------------------------------------------------
__device__ __forceinline__ void erode_from(const u64 S[][WPR], int y, u64 out[WPR]) {
  u64 c[WPR], up[WPR], dn[WPR];
#pragma unroll
  for (int k = 0; k < WPR; ++k) {
    c[k]  = S[y][k];
    up[k] = (y > 0)     ? S[y-1][k] : ~0ULL;
    dn[k] = (y < H-1)   ? S[y+1][k] : ~0ULL;
  }
#pragma unroll
  for (int k = 0; k < WPR; ++k) {
    u64 l = (c[k] << 1) | ((k > 0)     ? (c[k-1] >> 63) : 1ULL);
    u64 r = (c[k] >> 1) | ((k < WPR-1) ? (c[k+1] << 63) : 0x8000000000000000ULL);
    out[k] = c[k] & up[k] & dn[k] & l & r;
  }
}

__device__ __forceinline__ void dilate_from(const u64 S[][WPR], int y, u64 out[WPR]) {
  u64 v[WPR];
#pragma unroll
  for (int k = 0; k < WPR; ++k) {
    u64 a = S[y][k];
    if (y > 0)   a |= S[y-1][k];
    if (y < H-1) a |= S[y+1][k];
    v[k] = a;
  }
#pragma unroll
  for (int k = 0; k < WPR; ++k) {
    u64 l = (v[k] << 1) | ((k > 0)     ? (v[k-1] >> 63) : 0ULL);
    u64 r = (v[k] >> 1) | ((k < WPR-1) ? (v[k+1] << 63) : 0ULL);
    out[k] = v[k] | l | r;
  }
}

// ---------------------------------------------------------------------------
// K2: full soft_skel (10 iters) on a binary mask, bit-packed, in LDS.
// Block per (branch,image): 8 blocks, 256 threads (1 per row).
// Chain: E_{k+1} = erode(E_k); sk |= E_k & ~dilate(E_{k+1}).
// ONE barrier per level: the erode result is written into the dead buffer
// (its last readers all finished before the previous level's barrier), and
// the single barrier then publishes it for the dilate + next erode.
// ---------------------------------------------------------------------------
__global__ void skel_kernel(const u64* __restrict__ mask_bits,
                            u64* __restrict__ skel_bits) {
  __shared__ u64 SA[H][WPR];
  __shared__ u64 SB[H][WPR];
  int y = threadIdx.x;
  int base = blockIdx.x * WPI;
  u64 a[WPR], cur[WPR], e[WPR], d[WPR], sk[WPR];
#pragma unroll
  for (int k = 0; k < WPR; ++k) { a[k] = mask_bits[base + y*WPR + k]; SA[y][k] = a[k]; }
  __syncthreads();
  erode_from(SA, y, e);                 // E1 = erode(a)
#pragma unroll
  for (int k = 0; k < WPR; ++k) SB[y][k] = e[k];
  __syncthreads();                      // SB visible; all SA reads complete
  dilate_from(SB, y, d);                // open(a)
#pragma unroll
  for (int k = 0; k < WPR; ++k) { sk[k] = a[k] & ~d[k]; cur[k] = e[k]; }
  u64 (*P)[WPR] = SB;                   // holds current erosion level E_k
  u64 (*Q)[WPR] = SA;                   // dead buffer
  for (int it = 0; it < 10; ++it) {     // levels 1..10
    erode_from(P, y, e);                // E_{k+1}
#pragma unroll
    for (int k = 0; k < WPR; ++k) Q[y][k] = e[k];   // overwrite dead data
    __syncthreads();                    // publish Q; P reads all done
    dilate_from(Q, y, d);               // open(E_k)
#pragma unroll
    for (int k = 0; k < WPR; ++k) { sk[k] |= cur[k] & ~d[k]; cur[k] = e[k]; }
    u64 (*T)[WPR] = P; P = Q; Q = T;
  }
#pragma unroll
  for (int k = 0; k < WPR; ++k) skel_bits[base + y*WPR + k] = sk[k];
}

// ---------------------------------------------------------------------------
// K3 (fused): per (bi,x) column —
//   1. thread y computes horizontal EDT g(y,x) from bit-packed row (clz/ctz)
//   2. vertical lower envelope with EARLY EXIT: scan outward from yp=y,
//      stop when k^2 >= best (no farther candidate can win). Exact: the
//      scanned subset always contains the argmin; integer math in fp32.
//   3. writes edt; computes skel_radius; block-reduces rmax/rmin and
//      atomically merges into rmm_u (bit-cast uint ordering, floats >= 0).
// ---------------------------------------------------------------------------
__global__ void edt_cols_kernel(const u64* __restrict__ mask_bits,
                                const u64* __restrict__ skel_bits,
                                const float* __restrict__ pp,
                                float* __restrict__ edt,
                                unsigned* __restrict__ rmm_u) {
  __shared__ float col2[H];            // g^2 per row
  int bi = blockIdx.x >> 8;            // 0..7 = branch*4+img
  int x  = blockIdx.x & (W-1);
  int y  = threadIdx.x;
  const u64* row = mask_bits + bi*WPI + y*WPR;
  u64 z[WPR];
#pragma unroll
  for (int k = 0; k < WPR; ++k) z[k] = ~row[k];   // background bits
  int kx = x >> 6, bx = x & 63;
  int ld = 512;
  {
    u64 w = z[kx] & ((bx == 63) ? ~0ULL : ((1ULL << (bx+1)) - 1ULL));
    for (int k = kx; ; ) {
      if (w) { int pos = 63 - __builtin_clzll(w) + (k << 6); ld = x - pos; break; }
      if (--k < 0) break;
      w = z[k];
    }
  }
  int rd = 512;
  {
    u64 w = z[kx] & (~0ULL << bx);
    for (int k = kx; ; ) {
      if (w) { int pos = __builtin_ctzll(w) + (k << 6); rd = pos - x; break; }
      if (++k > WPR-1) break;
      w = z[k];
    }
  }
  int mb = (int)(((~z[kx]) >> bx) & 1ULL);        // mask bit at (y,x)
  int g = min(ld, rd);
  col2[y] = (float)(g * g);
  __syncthreads();
  float best = col2[y];                // k = 0 candidate
  for (int k = 1; k < H; ++k) {
    float k2 = (float)(k * k);
    if (k2 >= best) break;             // no farther candidate can improve
    int ym = y - k, yq = y + k;
    if (ym >= 0) best = fminf(best, col2[ym] + k2);
    if (yq < H)  best = fminf(best, col2[yq] + k2);
  }
  float dist = sqrtf(best);
  edt[bi*NPIX + y*W + x] = dist;
  // --- fused rmax/rmin of skel_radius ---
  int branch = bi >> 2, img = bi & 3;
  int sb = (int)((skel_bits[bi*WPI + y*WPR + kx] >> bx) & 1ULL);
  float distances = mb ? dist : 0.0f;
  bool skel;
  if (branch == 0) skel = (sb != 0);
  else             skel = ((sb ? pp[img*NPIX + y*W + x] : 0.0f) > 0.5f);
  float srad = skel ? distances : 0.0f;
  float vmax = srad, vmin = srad;
  for (int o = 32; o > 0; o >>= 1) {
    vmax = fmaxf(vmax, __shfl_down(vmax, o, 64));
    vmin = fminf(vmin, __shfl_down(vmin, o, 64));
  }
  __shared__ float smax[4], smin[4];
  int wave = y >> 6, lane = y & 63;
  if (lane == 0) { smax[wave] = vmax; smin[wave] = vmin; }
  __syncthreads();
  if (y == 0) {
    float mx = smax[0], mn = smin[0];
    for (int wv = 1; wv < 4; ++wv) { mx = fmaxf(mx, smax[wv]); mn = fminf(mn, smin[wv]); }
    atomicMax(&rmm_u[bi*2 + 0], __float_as_uint(mx));
    atomicMin(&rmm_u[bi*2 + 1], __float_as_uint(mn));
  }
}

// ---------------------------------------------------------------------------
// K4: per-pixel q terms + 4 global sums; last block computes the loss
// (atomic completion counter + device fence) — finalize fused in.
// ---------------------------------------------------------------------------
__global__ void final_sum_kernel(const float* __restrict__ edt,
                                 const u64* __restrict__ mask_bits,
                                 const u64* __restrict__ skel_bits,
                                 const float* __restrict__ pp,
                                 const unsigned* __restrict__ rmm_u,
                                 double* __restrict__ sums,
                                 unsigned* __restrict__ count,
                                 float* __restrict__ out) {
  int i = blockIdx.x * 256 + threadIdx.x;  // 0..NTOT-1
  int img = i >> 16;
  int wi = i >> 6;
  int b  = i & 63;
  // --- true branch (binary) ---
  int m_t = (int)((mask_bits[wi] >> b) & 1ULL);
  int s_t = (int)((skel_bits[wi] >> b) & 1ULL);
  float dist_t = edt[i];
  float rmax_t = fmaxf(__uint_as_float(rmm_u[img*2 + 0]), 1.0f);
  float rmin_t = fmaxf(__uint_as_float(rmm_u[img*2 + 1]), 1.0f);
  float distances_t = m_t ? dist_t : 0.0f;
  float skelrad_t   = s_t ? distances_t : 0.0f;
  float dmn_t = fminf(distances_t, rmax_t) / rmax_t;
  float srn_t = skelrad_t / rmax_t;
  float In_t  = s_t ? (rmax_t - skelrad_t + rmin_t) / rmax_t : 0.0f;
  float q_vl   = m_t ? dmn_t : 0.0f;
  float q_slvl = m_t ? srn_t : 0.0f;
  float q_sl   = s_t ? In_t  : 0.0f;
  // --- pred branch (probabilistic) ---
  int s_pb = (int)((skel_bits[WPB + wi] >> b) & 1ULL);
  float ppv = pp[i];
  float dist_p = edt[NTOT + i];
  float rmax_p = fmaxf(__uint_as_float(rmm_u[(4+img)*2 + 0]), 1.0f);
  float rmin_p = fmaxf(__uint_as_float(rmm_u[(4+img)*2 + 1]), 1.0f);
  float skel_in_p = s_pb ? ppv : 0.0f;      // skel_pred_prob
  bool msk_p = ppv > 0.5f;
  bool sk_p  = skel_in_p > 0.5f;
  float distances_p = msk_p ? dist_p : 0.0f;
  float skelrad_p   = sk_p ? distances_p : 0.0f;
  float dmn_p = fminf(distances_p, rmax_p) / rmax_p;
  float srn_p = skelrad_p / rmax_p;
  float In_p  = sk_p ? (rmax_p - skelrad_p + rmin_p) / rmax_p : 0.0f;
  float q_vp   = dmn_p * ppv;
  float q_spvp = srn_p * ppv;
  float q_sp   = In_p * skel_in_p;
  // --- the four sum terms ---
  float t1 = q_sp * q_vl;
  float t2 = (q_spvp != 0.0f && q_slvl == 0.0f) ? q_spvp * q_sp : q_slvl * q_sp;
  float t3 = q_sl * q_vp;
  float t4 = (q_slvl != 0.0f && q_spvp == 0.0f) ? q_slvl * q_sl : q_spvp * q_sl;
  for (int o = 32; o > 0; o >>= 1) {
    t1 += __shfl_down(t1, o, 64);
    t2 += __shfl_down(t2, o, 64);
    t3 += __shfl_down(t3, o, 64);
    t4 += __shfl_down(t4, o, 64);
  }
  __shared__ float part[4][4];
  int wave = threadIdx.x >> 6, lane = threadIdx.x & 63;
  if (lane == 0) { part[wave][0]=t1; part[wave][1]=t2; part[wave][2]=t3; part[wave][3]=t4; }
  __syncthreads();
  if (threadIdx.x == 0) {
    float a0=0,a1=0,a2=0,a3=0;
    for (int wv = 0; wv < 4; ++wv) {
      a0 += part[wv][0]; a1 += part[wv][1]; a2 += part[wv][2]; a3 += part[wv][3];
    }
    atomicAdd(&sums[0], (double)a0);
    atomicAdd(&sums[1], (double)a1);
    atomicAdd(&sums[2], (double)a2);
    atomicAdd(&sums[3], (double)a3);
    __threadfence();
    unsigned old = atomicAdd(count, 1u);
    if (old == gridDim.x - 1) {          // last block: epilogue
      double s0 = atomicAdd(&sums[0], 0.0);
      double s1 = atomicAdd(&sums[1], 0.0);
      double s2 = atomicAdd(&sums[2], 0.0);
      double s3 = atomicAdd(&sums[3], 0.0);
      double wp  = (s0 + 1.0) / (s1 + 1.0);
      double wsn = (s2 + 1.0) / (s3 + 1.0);
      out[0] = (float)(1.0 - 2.0 * (wp * wsn) / (wp + wsn));
    }
  }
}

extern "C" void kernel_launch(void* const* d_in, const int* in_sizes, int n_in,
                              void* d_out, int out_size, void* d_ws, size_t ws_size,
                              hipStream_t stream) {
  (void)in_sizes; (void)n_in; (void)out_size; (void)ws_size;
  const float* y_pred = (const float*)d_in[0];
  const int*   y_true = (const int*)d_in[1];
  float* out = (float*)d_out;
  char* ws = (char*)d_ws;

  // workspace layout (bytes)
  float* pp        = (float*)(ws + 0);          // 262144 f  (1,048,576 B)
  float* edt       = (float*)(ws + 1048576);    // 524288 f  (2,097,152 B) [branch][img][y][x]
  u64*   mask_bits = (u64*)  (ws + 3145728);    // 8192 u64  (65,536 B)
  u64*   skel_bits = (u64*)  (ws + 3211264);    // 8192 u64  (65,536 B)
  unsigned* rmm_u  = (unsigned*)(ws + 3276800); // 16 u32
  double* sums     = (double*)(ws + 3276864);   // 4 d
  unsigned* count  = (unsigned*)(ws + 3276896); // 1 u32

  prep_kernel<<<NTOT/256, 256, 0, stream>>>(y_pred, y_true, pp, mask_bits, rmm_u, sums, count);
  skel_kernel<<<8, 256, 0, stream>>>(mask_bits, skel_bits);
  edt_cols_kernel<<<8*W, 256, 0, stream>>>(mask_bits, skel_bits, pp, edt, rmm_u);
  final_sum_kernel<<<NTOT/256, 256, 0, stream>>>(edt, mask_bits, skel_bits, pp, rmm_u, sums, count, out);
}

// Round 5
// 138.049 us; speedup vs baseline: 1.3520x; 1.3520x over previous
//
#include <hip/hip_runtime.h>

typedef unsigned long long u64;

#define NIMG 4
#define H 256
#define W 256
#define NPIX (H*W)           // 65536 per image
#define NTOT (NIMG*NPIX)     // 262144
#define WPR 4                // u64 words per row (256 bits)
#define WPI (H*WPR)          // 1024 words per image
#define WPB (NIMG*WPI)       // 4096 words per branch

// ---------------------------------------------------------------------------
// K1: pp = sigmoid(2*sigmoid(y_pred)-1); pack yt and (pp>0.5) bitmasks.
// One wave (64 lanes) covers 64 consecutive pixels -> __ballot packs a word.
// Block 0 also initializes rmm (atomic identities) and sums.
// ---------------------------------------------------------------------------
__global__ void prep_kernel(const float* __restrict__ y_pred,
                            const int* __restrict__ y_true,
                            float* __restrict__ pp,
                            u64* __restrict__ mask_bits,
                            unsigned* __restrict__ rmm_u,
                            double* __restrict__ sums) {
  if (blockIdx.x == 0) {
    if (threadIdx.x < 16) rmm_u[threadIdx.x] = (threadIdx.x & 1) ? 0x7F800000u : 0u; // min:+inf, max:0
    else if (threadIdx.x < 20) sums[threadIdx.x - 16] = 0.0;
  }
  int i = blockIdx.x * 256 + threadIdx.x;
  float x = y_pred[i];
  float p = 1.0f / (1.0f + expf(-x));
  float q = 1.0f / (1.0f + expf(-(2.0f * p - 1.0f)));
  pp[i] = q;
  u64 bt = __ballot(y_true[i] > 0);
  u64 bp = __ballot(q > 0.5f);
  if ((threadIdx.x & 63) == 0) {
    mask_bits[i >> 6] = bt;          // branch 0: true mask
    mask_bits[WPB + (i >> 6)] = bp;  // branch 1: pred hard mask
  }
}

// ---------------------------------------------------------------------------
// Bit-parallel morphology helpers. Bit b of word k = pixel x = 64k+b.
// Erode = AND over cross {c, up, down, left, right}, OOB treated as 1.
// Dilate = OR over 3x3 box, OOB treated as 0.
// ---------------------------------------------------------------------------
__device__ __forceinline__ void erode_from(const u64 S[][WPR], int y, u64 out[WPR]) {
  u64 c[WPR], up[WPR], dn[WPR];
#pragma unroll
  for (int k = 0; k < WPR; ++k) {
    c[k]  = S[y][k];
    up[k] = (y > 0)     ? S[y-1][k] : ~0ULL;
    dn[k] = (y < H-1)   ? S[y+1][k] : ~0ULL;
  }
#pragma unroll
  for (int k = 0; k < WPR; ++k) {
    u64 l = (c[k] << 1) | ((k > 0)     ? (c[k-1] >> 63) : 1ULL);
    u64 r = (c[k] >> 1) | ((k < WPR-1) ? (c[k+1] << 63) : 0x8000000000000000ULL);
    out[k] = c[k] & up[k] & dn[k] & l & r;
  }
}

__device__ __forceinline__ void dilate_from(const u64 S[][WPR], int y, u64 out[WPR]) {
  u64 v[WPR];
#pragma unroll
  for (int k = 0; k < WPR; ++k) {
    u64 a = S[y][k];
    if (y > 0)   a |= S[y-1][k];
    if (y < H-1) a |= S[y+1][k];
    v[k] = a;
  }
#pragma unroll
  for (int k = 0; k < WPR; ++k) {
    u64 l = (v[k] << 1) | ((k > 0)     ? (v[k-1] >> 63) : 0ULL);
    u64 r = (v[k] >> 1) | ((k < WPR-1) ? (v[k+1] << 63) : 0ULL);
    out[k] = v[k] | l | r;
  }
}

// ---------------------------------------------------------------------------
// K2: full soft_skel (10 iters) on a binary mask, bit-packed, in LDS.
// Block per (branch,image): 8 blocks, 256 threads (1 per row).
// Chain: E_{k+1} = erode(E_k); sk |= E_k & ~dilate(E_{k+1}).
// ONE barrier per level (erode writes the dead buffer).
// ---------------------------------------------------------------------------
__global__ void skel_kernel(const u64* __restrict__ mask_bits,
                            u64* __restrict__ skel_bits) {
  __shared__ u64 SA[H][WPR];
  __shared__ u64 SB[H][WPR];
  int y = threadIdx.x;
  int base = blockIdx.x * WPI;
  u64 a[WPR], cur[WPR], e[WPR], d[WPR], sk[WPR];
#pragma unroll
  for (int k = 0; k < WPR; ++k) { a[k] = mask_bits[base + y*WPR + k]; SA[y][k] = a[k]; }
  __syncthreads();
  erode_from(SA, y, e);                 // E1 = erode(a)
#pragma unroll
  for (int k = 0; k < WPR; ++k) SB[y][k] = e[k];
  __syncthreads();                      // SB visible; all SA reads complete
  dilate_from(SB, y, d);                // open(a)
#pragma unroll
  for (int k = 0; k < WPR; ++k) { sk[k] = a[k] & ~d[k]; cur[k] = e[k]; }
  u64 (*P)[WPR] = SB;                   // holds current erosion level E_k
  u64 (*Q)[WPR] = SA;                   // dead buffer
  for (int it = 0; it < 10; ++it) {     // levels 1..10
    erode_from(P, y, e);                // E_{k+1}
#pragma unroll
    for (int k = 0; k < WPR; ++k) Q[y][k] = e[k];   // overwrite dead data
    __syncthreads();                    // publish Q; P reads all done
    dilate_from(Q, y, d);               // open(E_k)
#pragma unroll
    for (int k = 0; k < WPR; ++k) { sk[k] |= cur[k] & ~d[k]; cur[k] = e[k]; }
    u64 (*T)[WPR] = P; P = Q; Q = T;
  }
#pragma unroll
  for (int k = 0; k < WPR; ++k) skel_bits[base + y*WPR + k] = sk[k];
}

// ---------------------------------------------------------------------------
// K3 (fused): per (bi,x) column —
//   1. thread y computes horizontal EDT g(y,x) from bit-packed row (clz/ctz)
//   2. vertical lower envelope with EARLY EXIT (exact; integer math in fp32)
//   3. writes edt; fused block-reduced rmax/rmin -> atomic merge into rmm_u.
// ---------------------------------------------------------------------------
__global__ void edt_cols_kernel(const u64* __restrict__ mask_bits,
                                const u64* __restrict__ skel_bits,
                                const float* __restrict__ pp,
                                float* __restrict__ edt,
                                unsigned* __restrict__ rmm_u) {
  __shared__ float col2[H];            // g^2 per row
  int bi = blockIdx.x >> 8;            // 0..7 = branch*4+img
  int x  = blockIdx.x & (W-1);
  int y  = threadIdx.x;
  const u64* row = mask_bits + bi*WPI + y*WPR;
  u64 z[WPR];
#pragma unroll
  for (int k = 0; k < WPR; ++k) z[k] = ~row[k];   // background bits
  int kx = x >> 6, bx = x & 63;
  int ld = 512;
  {
    u64 w = z[kx] & ((bx == 63) ? ~0ULL : ((1ULL << (bx+1)) - 1ULL));
    for (int k = kx; ; ) {
      if (w) { int pos = 63 - __builtin_clzll(w) + (k << 6); ld = x - pos; break; }
      if (--k < 0) break;
      w = z[k];
    }
  }
  int rd = 512;
  {
    u64 w = z[kx] & (~0ULL << bx);
    for (int k = kx; ; ) {
      if (w) { int pos = __builtin_ctzll(w) + (k << 6); rd = pos - x; break; }
      if (++k > WPR-1) break;
      w = z[k];
    }
  }
  int mb = (int)(((~z[kx]) >> bx) & 1ULL);        // mask bit at (y,x)
  int g = min(ld, rd);
  col2[y] = (float)(g * g);
  __syncthreads();
  float best = col2[y];                // k = 0 candidate
  for (int k = 1; k < H; ++k) {
    float k2 = (float)(k * k);
    if (k2 >= best) break;             // no farther candidate can improve
    int ym = y - k, yq = y + k;
    if (ym >= 0) best = fminf(best, col2[ym] + k2);
    if (yq < H)  best = fminf(best, col2[yq] + k2);
  }
  float dist = sqrtf(best);
  edt[bi*NPIX + y*W + x] = dist;
  // --- fused rmax/rmin of skel_radius ---
  int branch = bi >> 2, img = bi & 3;
  int sb = (int)((skel_bits[bi*WPI + y*WPR + kx] >> bx) & 1ULL);
  float distances = mb ? dist : 0.0f;
  bool skel;
  if (branch == 0) skel = (sb != 0);
  else             skel = ((sb ? pp[img*NPIX + y*W + x] : 0.0f) > 0.5f);
  float srad = skel ? distances : 0.0f;
  float vmax = srad, vmin = srad;
  for (int o = 32; o > 0; o >>= 1) {
    vmax = fmaxf(vmax, __shfl_down(vmax, o, 64));
    vmin = fminf(vmin, __shfl_down(vmin, o, 64));
  }
  __shared__ float smax[4], smin[4];
  int wave = y >> 6, lane = y & 63;
  if (lane == 0) { smax[wave] = vmax; smin[wave] = vmin; }
  __syncthreads();
  if (y == 0) {
    float mx = smax[0], mn = smin[0];
    for (int wv = 1; wv < 4; ++wv) { mx = fmaxf(mx, smax[wv]); mn = fminf(mn, smin[wv]); }
    atomicMax(&rmm_u[bi*2 + 0], __float_as_uint(mx));
    atomicMin(&rmm_u[bi*2 + 1], __float_as_uint(mn));
  }
}

// ---------------------------------------------------------------------------
// K4: per-pixel q terms + 4 global sums. 4 pixels/thread via float4 loads
// (256 blocks); block reduce + 4 double atomics per block. NO device fence —
// visibility to finalize_kernel comes from the kernel boundary.
// ---------------------------------------------------------------------------
__global__ void final_sum_kernel(const float* __restrict__ edt,
                                 const u64* __restrict__ mask_bits,
                                 const u64* __restrict__ skel_bits,
                                 const float* __restrict__ pp,
                                 const unsigned* __restrict__ rmm_u,
                                 double* __restrict__ sums) {
  int i0 = (blockIdx.x * 256 + threadIdx.x) * 4;  // 0..NTOT-1, step 4
  int img = i0 >> 16;
  int wi = i0 >> 6;
  int b0 = i0 & 63;                               // b0 <= 60: 4 bits same word
  u64 mw_t = mask_bits[wi];
  u64 sw_t = skel_bits[wi];
  u64 sw_p = skel_bits[WPB + wi];
  float4 d_t4 = *(const float4*)(edt + i0);
  float4 d_p4 = *(const float4*)(edt + NTOT + i0);
  float4 pp4  = *(const float4*)(pp + i0);
  float rmax_t = fmaxf(__uint_as_float(rmm_u[img*2 + 0]), 1.0f);
  float rmin_t = fmaxf(__uint_as_float(rmm_u[img*2 + 1]), 1.0f);
  float rmax_p = fmaxf(__uint_as_float(rmm_u[(4+img)*2 + 0]), 1.0f);
  float rmin_p = fmaxf(__uint_as_float(rmm_u[(4+img)*2 + 1]), 1.0f);
  float t1 = 0.f, t2 = 0.f, t3 = 0.f, t4 = 0.f;
  float dts[4] = {d_t4.x, d_t4.y, d_t4.z, d_t4.w};
  float dps[4] = {d_p4.x, d_p4.y, d_p4.z, d_p4.w};
  float pps[4] = {pp4.x, pp4.y, pp4.z, pp4.w};
#pragma unroll
  for (int j = 0; j < 4; ++j) {
    int b = b0 + j;
    // --- true branch (binary) ---
    int m_t = (int)((mw_t >> b) & 1ULL);
    int s_t = (int)((sw_t >> b) & 1ULL);
    float distances_t = m_t ? dts[j] : 0.0f;
    float skelrad_t   = s_t ? distances_t : 0.0f;
    float dmn_t = fminf(distances_t, rmax_t) / rmax_t;
    float srn_t = skelrad_t / rmax_t;
    float In_t  = s_t ? (rmax_t - skelrad_t + rmin_t) / rmax_t : 0.0f;
    float q_vl   = m_t ? dmn_t : 0.0f;
    float q_slvl = m_t ? srn_t : 0.0f;
    float q_sl   = s_t ? In_t  : 0.0f;
    // --- pred branch (probabilistic) ---
    int s_pb = (int)((sw_p >> b) & 1ULL);
    float ppv = pps[j];
    float skel_in_p = s_pb ? ppv : 0.0f;      // skel_pred_prob
    bool msk_p = ppv > 0.5f;
    bool sk_p  = skel_in_p > 0.5f;
    float distances_p = msk_p ? dps[j] : 0.0f;
    float skelrad_p   = sk_p ? distances_p : 0.0f;
    float dmn_p = fminf(distances_p, rmax_p) / rmax_p;
    float srn_p = skelrad_p / rmax_p;
    float In_p  = sk_p ? (rmax_p - skelrad_p + rmin_p) / rmax_p : 0.0f;
    float q_vp   = dmn_p * ppv;
    float q_spvp = srn_p * ppv;
    float q_sp   = In_p * skel_in_p;
    t1 += q_sp * q_vl;
    t2 += (q_spvp != 0.0f && q_slvl == 0.0f) ? q_spvp * q_sp : q_slvl * q_sp;
    t3 += q_sl * q_vp;
    t4 += (q_slvl != 0.0f && q_spvp == 0.0f) ? q_slvl * q_sl : q_spvp * q_sl;
  }
  for (int o = 32; o > 0; o >>= 1) {
    t1 += __shfl_down(t1, o, 64);
    t2 += __shfl_down(t2, o, 64);
    t3 += __shfl_down(t3, o, 64);
    t4 += __shfl_down(t4, o, 64);
  }
  __shared__ float part[4][4];
  int wave = threadIdx.x >> 6, lane = threadIdx.x & 63;
  if (lane == 0) { part[wave][0]=t1; part[wave][1]=t2; part[wave][2]=t3; part[wave][3]=t4; }
  __syncthreads();
  if (threadIdx.x == 0) {
    float a0=0,a1=0,a2=0,a3=0;
    for (int wv = 0; wv < 4; ++wv) {
      a0 += part[wv][0]; a1 += part[wv][1]; a2 += part[wv][2]; a3 += part[wv][3];
    }
    atomicAdd(&sums[0], (double)a0);
    atomicAdd(&sums[1], (double)a1);
    atomicAdd(&sums[2], (double)a2);
    atomicAdd(&sums[3], (double)a3);
  }
}

// ---------------------------------------------------------------------------
// K5: scalar epilogue (kernel boundary = free device-wide release/acquire).
// ---------------------------------------------------------------------------
__global__ void finalize_kernel(const double* __restrict__ sums,
                                float* __restrict__ out) {
  double wp  = (sums[0] + 1.0) / (sums[1] + 1.0);
  double wsn = (sums[2] + 1.0) / (sums[3] + 1.0);
  double loss = 1.0 - 2.0 * (wp * wsn) / (wp + wsn);
  out[0] = (float)loss;
}

extern "C" void kernel_launch(void* const* d_in, const int* in_sizes, int n_in,
                              void* d_out, int out_size, void* d_ws, size_t ws_size,
                              hipStream_t stream) {
  (void)in_sizes; (void)n_in; (void)out_size; (void)ws_size;
  const float* y_pred = (const float*)d_in[0];
  const int*   y_true = (const int*)d_in[1];
  float* out = (float*)d_out;
  char* ws = (char*)d_ws;

  // workspace layout (bytes)
  float* pp        = (float*)(ws + 0);          // 262144 f  (1,048,576 B)
  float* edt       = (float*)(ws + 1048576);    // 524288 f  (2,097,152 B) [branch][img][y][x]
  u64*   mask_bits = (u64*)  (ws + 3145728);    // 8192 u64  (65,536 B)
  u64*   skel_bits = (u64*)  (ws + 3211264);    // 8192 u64  (65,536 B)
  unsigned* rmm_u  = (unsigned*)(ws + 3276800); // 16 u32
  double* sums     = (double*)(ws + 3276864);   // 4 d

  prep_kernel<<<NTOT/256, 256, 0, stream>>>(y_pred, y_true, pp, mask_bits, rmm_u, sums);
  skel_kernel<<<8, 256, 0, stream>>>(mask_bits, skel_bits);
  edt_cols_kernel<<<8*W, 256, 0, stream>>>(mask_bits, skel_bits, pp, edt, rmm_u);
  final_sum_kernel<<<NTOT/1024, 256, 0, stream>>>(edt, mask_bits, skel_bits, pp, rmm_u, sums);
  finalize_kernel<<<1, 1, 0, stream>>>(sums, out);
}

// Round 6
// 96.187 us; speedup vs baseline: 1.9403x; 1.4352x over previous
//
#include <hip/hip_runtime.h>

typedef unsigned long long u64;

#define NIMG 4
#define H 256
#define W 256
#define NPIX (H*W)           // 65536 per image
#define NTOT (NIMG*NPIX)     // 262144
#define WPR 4                // u64 words per row (256 bits)
#define WPI (H*WPR)          // 1024 words per image
#define WPB (NIMG*WPI)       // 4096 words per branch
#define XT 16                // columns per edt tile block

// ---------------------------------------------------------------------------
// K1: pp = sigmoid(2*sigmoid(y_pred)-1); pack yt and (pp>0.5) bitmasks.
// One wave (64 lanes) covers 64 consecutive pixels -> __ballot packs a word.
// Block 0 also initializes rmm (atomic identities) and sums.
// ---------------------------------------------------------------------------
__global__ void prep_kernel(const float* __restrict__ y_pred,
                            const int* __restrict__ y_true,
                            float* __restrict__ pp,
                            u64* __restrict__ mask_bits,
                            unsigned* __restrict__ rmm_u,
                            double* __restrict__ sums) {
  if (blockIdx.x == 0) {
    if (threadIdx.x < 16) rmm_u[threadIdx.x] = (threadIdx.x & 1) ? 0x7F800000u : 0u; // min:+inf, max:0
    else if (threadIdx.x < 20) sums[threadIdx.x - 16] = 0.0;
  }
  int i = blockIdx.x * 256 + threadIdx.x;
  float x = y_pred[i];
  float p = 1.0f / (1.0f + expf(-x));
  float q = 1.0f / (1.0f + expf(-(2.0f * p - 1.0f)));
  pp[i] = q;
  u64 bt = __ballot(y_true[i] > 0);
  u64 bp = __ballot(q > 0.5f);
  if ((threadIdx.x & 63) == 0) {
    mask_bits[i >> 6] = bt;          // branch 0: true mask
    mask_bits[WPB + (i >> 6)] = bp;  // branch 1: pred hard mask
  }
}

// ---------------------------------------------------------------------------
// Bit-parallel morphology helpers. Bit b of word k = pixel x = 64k+b.
// Erode = AND over cross {c, up, down, left, right}, OOB treated as 1.
// Dilate = OR over 3x3 box, OOB treated as 0.
// ---------------------------------------------------------------------------
__device__ __forceinline__ void erode_from(const u64 S[][WPR], int y, u64 out[WPR]) {
  u64 c[WPR], up[WPR], dn[WPR];
#pragma unroll
  for (int k = 0; k < WPR; ++k) {
    c[k]  = S[y][k];
    up[k] = (y > 0)     ? S[y-1][k] : ~0ULL;
    dn[k] = (y < H-1)   ? S[y+1][k] : ~0ULL;
  }
#pragma unroll
  for (int k = 0; k < WPR; ++k) {
    u64 l = (c[k] << 1) | ((k > 0)     ? (c[k-1] >> 63) : 1ULL);
    u64 r = (c[k] >> 1) | ((k < WPR-1) ? (c[k+1] << 63) : 0x8000000000000000ULL);
    out[k] = c[k] & up[k] & dn[k] & l & r;
  }
}

__device__ __forceinline__ void dilate_from(const u64 S[][WPR], int y, u64 out[WPR]) {
  u64 v[WPR];
#pragma unroll
  for (int k = 0; k < WPR; ++k) {
    u64 a = S[y][k];
    if (y > 0)   a |= S[y-1][k];
    if (y < H-1) a |= S[y+1][k];
    v[k] = a;
  }
#pragma unroll
  for (int k = 0; k < WPR; ++k) {
    u64 l = (v[k] << 1) | ((k > 0)     ? (v[k-1] >> 63) : 0ULL);
    u64 r = (v[k] >> 1) | ((k < WPR-1) ? (v[k+1] << 63) : 0ULL);
    out[k] = v[k] | l | r;
  }
}

// ---------------------------------------------------------------------------
// K2: full soft_skel (10 iters) on a binary mask, bit-packed, in LDS.
// Block per (branch,image): 8 blocks, 256 threads (1 per row).
// Chain: E_{k+1} = erode(E_k); sk |= E_k & ~dilate(E_{k+1}).
// ONE barrier per level (erode writes the dead buffer).
// ---------------------------------------------------------------------------
__global__ void skel_kernel(const u64* __restrict__ mask_bits,
                            u64* __restrict__ skel_bits) {
  __shared__ u64 SA[H][WPR];
  __shared__ u64 SB[H][WPR];
  int y = threadIdx.x;
  int base = blockIdx.x * WPI;
  u64 a[WPR], cur[WPR], e[WPR], d[WPR], sk[WPR];
#pragma unroll
  for (int k = 0; k < WPR; ++k) { a[k] = mask_bits[base + y*WPR + k]; SA[y][k] = a[k]; }
  __syncthreads();
  erode_from(SA, y, e);                 // E1 = erode(a)
#pragma unroll
  for (int k = 0; k < WPR; ++k) SB[y][k] = e[k];
  __syncthreads();                      // SB visible; all SA reads complete
  dilate_from(SB, y, d);                // open(a)
#pragma unroll
  for (int k = 0; k < WPR; ++k) { sk[k] = a[k] & ~d[k]; cur[k] = e[k]; }
  u64 (*P)[WPR] = SB;                   // holds current erosion level E_k
  u64 (*Q)[WPR] = SA;                   // dead buffer
  for (int it = 0; it < 10; ++it) {     // levels 1..10
    erode_from(P, y, e);                // E_{k+1}
#pragma unroll
    for (int k = 0; k < WPR; ++k) Q[y][k] = e[k];   // overwrite dead data
    __syncthreads();                    // publish Q; P reads all done
    dilate_from(Q, y, d);               // open(E_k)
#pragma unroll
    for (int k = 0; k < WPR; ++k) { sk[k] |= cur[k] & ~d[k]; cur[k] = e[k]; }
    u64 (*T)[WPR] = P; P = Q; Q = T;
  }
#pragma unroll
  for (int k = 0; k < WPR; ++k) skel_bits[base + y*WPR + k] = sk[k];
}

// ---------------------------------------------------------------------------
// K3 (tiled): block per (bi, 16-column tile). 128 blocks x 256 threads.
// Phase 1: thread = row y. One coalesced 32B bit-row load; compute horizontal
//          EDT g (clz/ctz) for the tile's 16 columns -> LDS col2[y][xx] (g^2).
// Phase 2: thread = (x in tile, ygrp of 16 rows). Early-exit vertical lower
//          envelope over LDS column (exact: scanned subset contains argmin;
//          integer math in fp32). Row-major coalesced edt store (full 64B
//          sectors). srad = skel_bit ? dist : 0 for BOTH branches, because
//          dist==0 iff mask==0 and (pp>0.5) IS the pred mask bit -> no pp
//          load, no mask load here. Fused block rmax/rmin -> atomic merge.
// LDS pad 17: phase-2 reads are 2-way bank-aliased (free on gfx950).
// ---------------------------------------------------------------------------
__global__ void edt_cols_kernel(const u64* __restrict__ mask_bits,
                                const u64* __restrict__ skel_bits,
                                float* __restrict__ edt,
                                unsigned* __restrict__ rmm_u) {
  __shared__ float col2[H][XT + 1];
  int bi = blockIdx.x >> 4;            // 0..7 = branch*4+img
  int xt = blockIdx.x & 15;
  int x0 = xt * XT;
  int kx = x0 >> 6;                    // all tile columns in this u64 word
  int sh0 = x0 & 63;
  int t = threadIdx.x;
  // ---- phase 1: horizontal distances for the tile ----
  {
    int y = t;
    const u64* row = mask_bits + bi*WPI + y*WPR;
    u64 z[WPR];
#pragma unroll
    for (int k = 0; k < WPR; ++k) z[k] = ~row[k];   // background bits
#pragma unroll
    for (int xx = 0; xx < XT; ++xx) {
      int x = x0 + xx;
      int bx = x & 63;
      int ld = 512;
      {
        u64 w = z[kx] & ((bx == 63) ? ~0ULL : ((1ULL << (bx+1)) - 1ULL));
        for (int k = kx; ; ) {
          if (w) { int pos = 63 - __builtin_clzll(w) + (k << 6); ld = x - pos; break; }
          if (--k < 0) break;
          w = z[k];
        }
      }
      int rd = 512;
      {
        u64 w = z[kx] & (~0ULL << bx);
        for (int k = kx; ; ) {
          if (w) { int pos = __builtin_ctzll(w) + (k << 6); rd = pos - x; break; }
          if (++k > WPR-1) break;
          w = z[k];
        }
      }
      int g = min(ld, rd);
      col2[y][xx] = (float)(g * g);
    }
  }
  __syncthreads();
  // ---- phase 2: vertical envelope + store + rmax/rmin ----
  int x  = t & (XT - 1);               // 0..15
  int yg = t >> 4;                     // 0..15, rows yg*16..yg*16+15
  float vmax = 0.0f, vmin = 3.0e38f;
#pragma unroll
  for (int j = 0; j < 16; ++j) {
    int y = yg * 16 + j;
    float best = col2[y][x];           // k = 0 candidate
    for (int k = 1; k < H; ++k) {
      float k2 = (float)(k * k);
      if (k2 >= best) break;           // no farther candidate can improve
      int ym = y - k, yq = y + k;
      if (ym >= 0) best = fminf(best, col2[ym][x] + k2);
      if (yq < H)  best = fminf(best, col2[yq][x] + k2);
    }
    float dist = sqrtf(best);
    edt[bi*NPIX + y*W + x0 + x] = dist;
    u64 sw = skel_bits[bi*WPI + y*WPR + kx];
    int sb = (int)((sw >> (sh0 + x)) & 1ULL);
    float srad = sb ? dist : 0.0f;     // == skel_radius for both branches
    vmax = fmaxf(vmax, srad);
    vmin = fminf(vmin, srad);
  }
  for (int o = 32; o > 0; o >>= 1) {
    vmax = fmaxf(vmax, __shfl_down(vmax, o, 64));
    vmin = fminf(vmin, __shfl_down(vmin, o, 64));
  }
  __shared__ float smax[4], smin[4];
  int wave = t >> 6, lane = t & 63;
  if (lane == 0) { smax[wave] = vmax; smin[wave] = vmin; }
  __syncthreads();
  if (t == 0) {
    float mx = smax[0], mn = smin[0];
    for (int wv = 1; wv < 4; ++wv) { mx = fmaxf(mx, smax[wv]); mn = fminf(mn, smin[wv]); }
    atomicMax(&rmm_u[bi*2 + 0], __float_as_uint(mx));
    atomicMin(&rmm_u[bi*2 + 1], __float_as_uint(mn));
  }
}

// ---------------------------------------------------------------------------
// K4: per-pixel q terms + 4 global sums. 4 pixels/thread via float4 loads
// (256 blocks); block reduce + 4 double atomics per block. NO device fence —
// visibility to finalize_kernel comes from the kernel boundary.
// ---------------------------------------------------------------------------
__global__ void final_sum_kernel(const float* __restrict__ edt,
                                 const u64* __restrict__ mask_bits,
                                 const u64* __restrict__ skel_bits,
                                 const float* __restrict__ pp,
                                 const unsigned* __restrict__ rmm_u,
                                 double* __restrict__ sums) {
  int i0 = (blockIdx.x * 256 + threadIdx.x) * 4;  // 0..NTOT-1, step 4
  int img = i0 >> 16;
  int wi = i0 >> 6;
  int b0 = i0 & 63;                               // b0 <= 60: 4 bits same word
  u64 mw_t = mask_bits[wi];
  u64 sw_t = skel_bits[wi];
  u64 sw_p = skel_bits[WPB + wi];
  float4 d_t4 = *(const float4*)(edt + i0);
  float4 d_p4 = *(const float4*)(edt + NTOT + i0);
  float4 pp4  = *(const float4*)(pp + i0);
  float rmax_t = fmaxf(__uint_as_float(rmm_u[img*2 + 0]), 1.0f);
  float rmin_t = fmaxf(__uint_as_float(rmm_u[img*2 + 1]), 1.0f);
  float rmax_p = fmaxf(__uint_as_float(rmm_u[(4+img)*2 + 0]), 1.0f);
  float rmin_p = fmaxf(__uint_as_float(rmm_u[(4+img)*2 + 1]), 1.0f);
  float t1 = 0.f, t2 = 0.f, t3 = 0.f, t4 = 0.f;
  float dts[4] = {d_t4.x, d_t4.y, d_t4.z, d_t4.w};
  float dps[4] = {d_p4.x, d_p4.y, d_p4.z, d_p4.w};
  float pps[4] = {pp4.x, pp4.y, pp4.z, pp4.w};
#pragma unroll
  for (int j = 0; j < 4; ++j) {
    int b = b0 + j;
    // --- true branch (binary) ---
    int m_t = (int)((mw_t >> b) & 1ULL);
    int s_t = (int)((sw_t >> b) & 1ULL);
    float distances_t = m_t ? dts[j] : 0.0f;
    float skelrad_t   = s_t ? distances_t : 0.0f;
    float dmn_t = fminf(distances_t, rmax_t) / rmax_t;
    float srn_t = skelrad_t / rmax_t;
    float In_t  = s_t ? (rmax_t - skelrad_t + rmin_t) / rmax_t : 0.0f;
    float q_vl   = m_t ? dmn_t : 0.0f;
    float q_slvl = m_t ? srn_t : 0.0f;
    float q_sl   = s_t ? In_t  : 0.0f;
    // --- pred branch (probabilistic) ---
    int s_pb = (int)((sw_p >> b) & 1ULL);
    float ppv = pps[j];
    float skel_in_p = s_pb ? ppv : 0.0f;      // skel_pred_prob
    bool msk_p = ppv > 0.5f;
    bool sk_p  = skel_in_p > 0.5f;
    float distances_p = msk_p ? dps[j] : 0.0f;
    float skelrad_p   = sk_p ? distances_p : 0.0f;
    float dmn_p = fminf(distances_p, rmax_p) / rmax_p;
    float srn_p = skelrad_p / rmax_p;
    float In_p  = sk_p ? (rmax_p - skelrad_p + rmin_p) / rmax_p : 0.0f;
    float q_vp   = dmn_p * ppv;
    float q_spvp = srn_p * ppv;
    float q_sp   = In_p * skel_in_p;
    t1 += q_sp * q_vl;
    t2 += (q_spvp != 0.0f && q_slvl == 0.0f) ? q_spvp * q_sp : q_slvl * q_sp;
    t3 += q_sl * q_vp;
    t4 += (q_slvl != 0.0f && q_spvp == 0.0f) ? q_slvl * q_sl : q_spvp * q_sl;
  }
  for (int o = 32; o > 0; o >>= 1) {
    t1 += __shfl_down(t1, o, 64);
    t2 += __shfl_down(t2, o, 64);
    t3 += __shfl_down(t3, o, 64);
    t4 += __shfl_down(t4, o, 64);
  }
  __shared__ float part[4][4];
  int wave = threadIdx.x >> 6, lane = threadIdx.x & 63;
  if (lane == 0) { part[wave][0]=t1; part[wave][1]=t2; part[wave][2]=t3; part[wave][3]=t4; }
  __syncthreads();
  if (threadIdx.x == 0) {
    float a0=0,a1=0,a2=0,a3=0;
    for (int wv = 0; wv < 4; ++wv) {
      a0 += part[wv][0]; a1 += part[wv][1]; a2 += part[wv][2]; a3 += part[wv][3];
    }
    atomicAdd(&sums[0], (double)a0);
    atomicAdd(&sums[1], (double)a1);
    atomicAdd(&sums[2], (double)a2);
    atomicAdd(&sums[3], (double)a3);
  }
}

// ---------------------------------------------------------------------------
// K5: scalar epilogue (kernel boundary = free device-wide release/acquire).
// ---------------------------------------------------------------------------
__global__ void finalize_kernel(const double* __restrict__ sums,
                                float* __restrict__ out) {
  double wp  = (sums[0] + 1.0) / (sums[1] + 1.0);
  double wsn = (sums[2] + 1.0) / (sums[3] + 1.0);
  double loss = 1.0 - 2.0 * (wp * wsn) / (wp + wsn);
  out[0] = (float)loss;
}

extern "C" void kernel_launch(void* const* d_in, const int* in_sizes, int n_in,
                              void* d_out, int out_size, void* d_ws, size_t ws_size,
                              hipStream_t stream) {
  (void)in_sizes; (void)n_in; (void)out_size; (void)ws_size;
  const float* y_pred = (const float*)d_in[0];
  const int*   y_true = (const int*)d_in[1];
  float* out = (float*)d_out;
  char* ws = (char*)d_ws;

  // workspace layout (bytes)
  float* pp        = (float*)(ws + 0);          // 262144 f  (1,048,576 B)
  float* edt       = (float*)(ws + 1048576);    // 524288 f  (2,097,152 B) [branch][img][y][x]
  u64*   mask_bits = (u64*)  (ws + 3145728);    // 8192 u64  (65,536 B)
  u64*   skel_bits = (u64*)  (ws + 3211264);    // 8192 u64  (65,536 B)
  unsigned* rmm_u  = (unsigned*)(ws + 3276800); // 16 u32
  double* sums     = (double*)(ws + 3276864);   // 4 d

  prep_kernel<<<NTOT/256, 256, 0, stream>>>(y_pred, y_true, pp, mask_bits, rmm_u, sums);
  skel_kernel<<<8, 256, 0, stream>>>(mask_bits, skel_bits);
  edt_cols_kernel<<<8*(W/XT), 256, 0, stream>>>(mask_bits, skel_bits, edt, rmm_u);
  final_sum_kernel<<<NTOT/1024, 256, 0, stream>>>(edt, mask_bits, skel_bits, pp, rmm_u, sums);
  finalize_kernel<<<1, 1, 0, stream>>>(sums, out);
}